// Round 11
// baseline (231.275 us; speedup 1.0000x reference)
//
#include <hip/hip_runtime.h>
#include <hip/hip_fp16.h>

#define N_PIX 196608
#define KNN 32
// CHANNELS = 4, BATCH = 8 (split into 2 halves of 4)

typedef float f4v __attribute__((ext_vector_type(4)));
typedef unsigned int u4v __attribute__((ext_vector_type(4)));

// ws layout:
//   [0, XS_BYTES)        xs   : fp16 x/rowsum, layout [half][n][bq][c]  (8B per (n,bq))
//   [+PK_BYTES)          pack : u32 per (n,k): (j << 14) | w14
//   [+RS_BYTES)          inv_rs
//   [+4)                 flag (1 = inds int64)
#define XS_BYTES ((size_t)N_PIX * 64)
#define PK_BYTES ((size_t)N_PIX * KNN * 4)
#define RS_BYTES ((size_t)N_PIX * 4)

__device__ __forceinline__ unsigned int pack_h2(float a, float b) {
    __half2 h = __floats2half2_rn(a, b);
    return *reinterpret_cast<unsigned int*>(&h);
}

__global__ void k_detect(const unsigned int* __restrict__ inds_u32, int* __restrict__ flag) {
    unsigned int v = inds_u32[threadIdx.x * 2 + 1];
    unsigned long long bal = __ballot(v != 0);
    if (threadIdx.x == 0) *flag = (bal == 0ULL) ? 1 : 0;
}

// Thread per (n, k4): pack 4 (index,weight) pairs; fused rowsum (8 lanes/pixel).
template <int STRIDE>
__device__ __forceinline__ void pack_body(int n, int k4, const char* __restrict__ ib,
                                          const float* __restrict__ kern,
                                          unsigned int* __restrict__ packed,
                                          float* __restrict__ inv_rs) {
    int j[4];
    if (STRIDE == 8) {
        const u4v* p = reinterpret_cast<const u4v*>(ib + (size_t)n * KNN * 8 + k4 * 32);
        u4v a = p[0], b = p[1];
        j[0] = a.x; j[1] = a.z; j[2] = b.x; j[3] = b.z;   // low dwords of int64
    } else {
        u4v a = *reinterpret_cast<const u4v*>(ib + (size_t)n * KNN * 4 + k4 * 16);
        j[0] = a.x; j[1] = a.y; j[2] = a.z; j[3] = a.w;
    }
    f4v kv = *reinterpret_cast<const f4v*>(kern + (size_t)n * KNN + k4 * 4);
    float s = kv[0] + kv[1] + kv[2] + kv[3];
    s += __shfl_xor(s, 1);
    s += __shfl_xor(s, 2);
    s += __shfl_xor(s, 4);
    if (k4 == 0) inv_rs[n] = 1.0f / s;
    u4v pk;
#pragma unroll
    for (int u = 0; u < 4; ++u) {
        unsigned int wq = (unsigned int)__float2int_rn(kv[u] * 16383.0f);
        wq = wq > 16383u ? 16383u : wq;
        pk[u] = ((unsigned int)j[u] << 14) | wq;
    }
    *reinterpret_cast<u4v*>(packed + (size_t)n * KNN + k4 * 4) = pk;
}

__global__ __launch_bounds__(256) void k_pack(const float* __restrict__ kern,
                                              const void* __restrict__ inds,
                                              const int* __restrict__ flag,
                                              unsigned int* __restrict__ packed,
                                              float* __restrict__ inv_rs) {
    int tid = blockIdx.x * 256 + threadIdx.x;        // [0, N_PIX*8)
    int n = tid >> 3, k4 = tid & 7;
    const char* ib = reinterpret_cast<const char*>(inds);
    if (*flag) pack_body<8>(n, k4, ib, kern, packed, inv_rs);
    else       pack_body<4>(n, k4, ib, kern, packed, inv_rs);
}

// xs[half][n][bq][c] = fp16( x[b,n,c] * inv_rs[n] ),  b = half*4+bq. Block: 32 pixels.
__global__ __launch_bounds__(256) void k_xs(const float* __restrict__ x,
                                            const float* __restrict__ inv_rs,
                                            uint2* __restrict__ xs) {
    __shared__ uint2 tile[32][9];                    // +1 pad
    int n0 = blockIdx.x * 32, t = threadIdx.x;
    int b = t >> 5, i = t & 31;
    f4v u = reinterpret_cast<const f4v*>(x)[(size_t)b * N_PIX + n0 + i];  // coalesced
    float r = inv_rs[n0 + i];
    uint2 p;
    p.x = pack_h2(u[0] * r, u[1] * r);
    p.y = pack_h2(u[2] * r, u[3] * r);
    tile[i][b] = p;
    __syncthreads();
    int P = t >> 7, rem = t & 127, row = rem >> 2, bq = rem & 3;
    xs[((size_t)P * N_PIX + n0 + row) * 4 + bq] = tile[row][P * 4 + bq];  // 1KB contig/half
}

// One batch-half: thread per (n, bq). Lanes 0..3 share n -> one 32B segment
// per gather. Per-pass gather footprint = N*32B = 6.3MB (fits-ish in 4MB L2).
__global__ __launch_bounds__(256, 8) void k_gmain(const unsigned int* __restrict__ packed,
                                                  const uint2* __restrict__ xsh,
                                                  float* __restrict__ outh) {
    int tid = blockIdx.x * 256 + threadIdx.x;        // [0, N_PIX*4)
    int n = tid >> 2, bq = tid & 3;
    const u4v* pk = reinterpret_cast<const u4v*>(packed) + (size_t)n * 8;
    f4v acc = (f4v)0.0f;

#pragma unroll 2
    for (int k0 = 0; k0 < 8; ++k0) {
        u4v pq = __builtin_nontemporal_load(pk + k0);
        uint2 g[4];
#pragma unroll
        for (int u = 0; u < 4; ++u) g[u] = xsh[(size_t)(pq[u] >> 14) * 4 + bq];  // cached
#pragma unroll
        for (int u = 0; u < 4; ++u) {
            float w = (float)(pq[u] & 0x3FFFu) * (1.0f / 16383.0f);
            float2 f0 = __half22float2(*reinterpret_cast<__half2*>(&g[u].x));
            float2 f1 = __half22float2(*reinterpret_cast<__half2*>(&g[u].y));
            acc[0] = fmaf(w, f0.x, acc[0]);
            acc[1] = fmaf(w, f0.y, acc[1]);
            acc[2] = fmaf(w, f1.x, acc[2]);
            acc[3] = fmaf(w, f1.y, acc[3]);
        }
    }
    __builtin_nontemporal_store(acc, reinterpret_cast<f4v*>(outh) + (size_t)bq * N_PIX + n);
}

extern "C" void kernel_launch(void* const* d_in, const int* in_sizes, int n_in,
                              void* d_out, int out_size, void* d_ws, size_t ws_size,
                              hipStream_t stream) {
    const float* x    = (const float*)d_in[0];
    const float* kern = (const float*)d_in[1];
    const void*  inds = d_in[2];
    float* out = (float*)d_out;

    uint2*        xs     = (uint2*)d_ws;
    unsigned int* packed = (unsigned int*)((char*)d_ws + XS_BYTES);
    float*        inv_rs = (float*)((char*)d_ws + XS_BYTES + PK_BYTES);
    int*          flag   = (int*)((char*)d_ws + XS_BYTES + PK_BYTES + RS_BYTES);

    k_detect<<<1, 64, 0, stream>>>((const unsigned int*)inds, flag);
    k_pack<<<(N_PIX * 8) / 256, 256, 0, stream>>>(kern, inds, flag, packed, inv_rs);
    k_xs<<<N_PIX / 32, 256, 0, stream>>>(x, inv_rs, xs);
    // pass 0: batches 0-3, pass 1: batches 4-7
    k_gmain<<<(N_PIX * 4) / 256, 256, 0, stream>>>(packed, xs, out);
    k_gmain<<<(N_PIX * 4) / 256, 256, 0, stream>>>(packed, xs + (size_t)N_PIX * 4,
                                                   out + (size_t)N_PIX * 16);
}